// Round 1
// 426.575 us; speedup vs baseline: 1.2373x; 1.2373x over previous
//
#include <hip/hip_runtime.h>
#include <math.h>

// ---------------- problem constants ----------------
#define BB_ 64
#define P_  24
#define C_  40
#define WIN_ 64
#define L1_ 60
#define L2_ 56
#define R_  1344

// ---------------- ws layout (float offsets) ----------------
// usq [0, 2752512)
// uhat (bf16, 55050240 ushorts = 27525120 floats) at [2752512, 30277632)
// hb/wt/up overlay inside uhat region (dead before k6 writes uhat)
#define O_USQ   0ull
#define O_UHAT  2752512ull
#define O_H     30277632ull         // hpre: 64*60*256 = 983040 floats (outside uhat region)
#define O_HB    3735552ull          // bf16 h: 983040 ushorts = 491520 floats
#define O_WT    4227072ull          // bf16 wt: 983040 ushorts = 491520 floats
#define O_UP    25755648ull         // 2752512 floats, alias in uhat region
#define O_STATS 57802752ull
#define O_A1    57803328ull
#define O_B1S   57803584ull
#define O_A2    57803840ull
#define O_B2S   57803872ull
#define O_S     57803904ull         // s0,s1,s2,vsum each 40960
#define O_V     57967744ull
#define WS_FLOATS_NEEDED 58008704ull

typedef short bf16x8 __attribute__((ext_vector_type(8)));
typedef float f32x4 __attribute__((ext_vector_type(4)));

__device__ __forceinline__ float dot4f(float4 a, float4 b) {
    return a.x*b.x + a.y*b.y + a.z*b.z + a.w*b.w;
}

__device__ __forceinline__ unsigned short f2bf(float x) {
    unsigned int u = __float_as_uint(x);
    u += 0x7fffu + ((u >> 16) & 1u);       // RTNE
    return (unsigned short)(u >> 16);
}
__device__ __forceinline__ float bfl(unsigned int u) {   // low ushort -> float
    return __uint_as_float(u << 16);
}
__device__ __forceinline__ float bfh(unsigned int u) {   // high ushort -> float
    return __uint_as_float(u & 0xffff0000u);
}

// ============ K0w: transpose prim_w (768,256,5) -> bf16 wt[kt][o2][ic] ============
__global__ void k0w(const float* __restrict__ w2, unsigned short* __restrict__ wt) {
    int o2 = blockIdx.x, t = threadIdx.x;   // t = ic (0..255)
    const float* src = &w2[(size_t)o2 * 1280 + t * 5];
    #pragma unroll
    for (int kt = 0; kt < 5; kt++)
        wt[((size_t)kt * 768 + o2) * 256 + t] = f2bf(src[kt]);
}

// ============ K1: conv1 (24->256, k=5) + bias, h layout (b, l, o) ============
__global__ void k1_conv1(const float* __restrict__ x, const float* __restrict__ w1,
                         const float* __restrict__ c1b, float* __restrict__ h) {
    __shared__ float xs[24 * 20];
    __shared__ float wl[64 * 121];
    int t = threadIdx.x;
    int lq = blockIdx.x, b = blockIdx.y, ocg = blockIdx.z;
    for (int idx = t; idx < 456; idx += 256) {
        int p = idx / 19, tau = idx - p * 19;
        xs[p * 20 + tau] = x[b * 1536 + (lq * 15 + tau) * 24 + p];
    }
    for (int idx = t; idx < 7680; idx += 256) {
        int o_ = idx / 120, cix = idx - o_ * 120;
        wl[o_ * 121 + cix] = w1[(ocg * 64 + o_) * 120 + cix];
    }
    __syncthreads();
    int g = t >> 6;
    int ol = t & 63;
    int LV = (g < 3) ? 4 : 3;
    int o = ocg * 64 + ol;
    float acc[4] = {0.f, 0.f, 0.f, 0.f};
    for (int p = 0; p < 24; p++) {
        float4 xa = *(const float4*)&xs[p * 20 + g * 4];
        float4 xb = *(const float4*)&xs[p * 20 + g * 4 + 4];
        float xr[8] = {xa.x, xa.y, xa.z, xa.w, xb.x, xb.y, xb.z, xb.w};
        #pragma unroll
        for (int k = 0; k < 5; k++) {
            float w = wl[ol * 121 + p * 5 + k];
            #pragma unroll
            for (int li = 0; li < 4; li++) acc[li] += xr[li + k] * w;
        }
    }
    for (int li = 0; li < LV; li++) {
        int l = lq * 15 + g * 4 + li;
        h[(size_t)(b * 60 + l) * 256 + o] = acc[li] + c1b[o];
    }
}

// ============ K2a: BN1 stats ============
__global__ void k2a(const float* __restrict__ h, float* __restrict__ sum1, float* __restrict__ ss1) {
    int t = threadIdx.x;
    float s = 0.f, q = 0.f;
    for (int i = 0; i < 64; i++) {
        float v = h[(size_t)(blockIdx.x * 64 + i) * 256 + t];
        s += v; q += v * v;
    }
    atomicAdd(&sum1[t], s);
    atomicAdd(&ss1[t], q);
}

__global__ void k2b(const float* __restrict__ sum1, const float* __restrict__ ss1,
                    const float* __restrict__ g, const float* __restrict__ be,
                    float* __restrict__ a1, float* __restrict__ b1s) {
    int o = threadIdx.x;
    float m = sum1[o] * (1.f / 3840.f);
    float v = ss1[o] * (1.f / 3840.f) - m * m;
    float a = g[o] / sqrtf(v + 1e-5f);
    a1[o] = a;
    b1s[o] = be[o] - m * a;
}

// ============ K2c: BN1+ReLU apply + bf16 convert -> hb[b][l][ic] ============
__global__ void k2c(const float* __restrict__ h, const float* __restrict__ a1,
                    const float* __restrict__ b1s, unsigned short* __restrict__ hb) {
    int gid = blockIdx.x * 256 + threadIdx.x;   // 0..245759
    int base = gid * 4;
    int ic = base & 255;
    float4 v = *(const float4*)&h[base];
    float4 a = *(const float4*)&a1[ic];
    float4 bb = *(const float4*)&b1s[ic];
    unsigned int w0 = (unsigned int)f2bf(fmaxf(v.x * a.x + bb.x, 0.f))
                    | ((unsigned int)f2bf(fmaxf(v.y * a.y + bb.y, 0.f)) << 16);
    unsigned int w1 = (unsigned int)f2bf(fmaxf(v.z * a.z + bb.z, 0.f))
                    | ((unsigned int)f2bf(fmaxf(v.w * a.w + bb.w, 0.f)) << 16);
    uint2 o = {w0, w1};
    *(uint2*)&hb[base] = o;
}

// ============ K3: primary conv as bf16 MFMA GEMM ============
// GEMM: up[b][l][o2] = sum_{kt,ic} W[o2][ic][kt] * hrelu[b][l+kt][ic], + pb[o2]
// grid (12 m-tiles, 64 batches), block 256 (4 waves, 2x2 wave grid, 2x2 subtiles each).
// M_BLK=64 (o2), N_BLK=64 (l, padded; l<56 valid). K-loop: 8 ic-chunks x 5 taps.
// h staged once per ic-chunk, taps read as shifted LDS rows. Rows padded to 40 bf16
// (80B) so stride-row ds_read_b128 frag loads are 2-way (free) on the 32 banks.
__global__ __launch_bounds__(256) void k3_mfma(
        const unsigned short* __restrict__ hb, const unsigned short* __restrict__ wt,
        const float* __restrict__ pb, float* __restrict__ up) {
    __shared__ unsigned short hs[68 * 40];        // rows l=0..67 (clamped to 59), 32 ic + pad
    __shared__ unsigned short wsd[5 * 64 * 40];   // [kt][o2_local][ic + pad]
    int t = threadIdx.x;
    int m0 = blockIdx.x * 64;
    int b = blockIdx.y;
    int wid = t >> 6, lane = t & 63;
    int wm = wid >> 1, wn = wid & 1;
    int ln = lane & 15, grp = lane >> 4;

    f32x4 acc[2][2];
    #pragma unroll
    for (int i = 0; i < 2; i++)
        #pragma unroll
        for (int j = 0; j < 2; j++) acc[i][j] = (f32x4){0.f, 0.f, 0.f, 0.f};

    for (int ic0 = 0; ic0 < 256; ic0 += 32) {
        __syncthreads();
        // stage h: 68 rows x 32 ic (bf16), 272 uint4
        for (int idx = t; idx < 272; idx += 256) {
            int row = idx >> 2, q = idx & 3;
            int hrow = row < 60 ? row : 59;      // rows >=60 feed only discarded cols
            uint4 v = *(const uint4*)&hb[((size_t)b * 60 + hrow) * 256 + ic0 + q * 8];
            *(uint4*)&hs[row * 40 + q * 8] = v;
        }
        // stage W: 5 kt x 64 o2 x 32 ic (bf16), 1280 uint4
        #pragma unroll
        for (int it = 0; it < 5; it++) {
            int idx = it * 256 + t;
            int row = idx >> 2, q = idx & 3;     // row = kt*64 + o2l
            int kt = row >> 6, o2l = row & 63;
            uint4 v = *(const uint4*)&wt[((size_t)kt * 768 + m0 + o2l) * 256 + ic0 + q * 8];
            *(uint4*)&wsd[row * 40 + q * 8] = v;
        }
        __syncthreads();
        #pragma unroll
        for (int kt = 0; kt < 5; kt++) {
            bf16x8 af0 = *(const bf16x8*)&wsd[(kt * 64 + wm * 32 + ln) * 40 + grp * 8];
            bf16x8 af1 = *(const bf16x8*)&wsd[(kt * 64 + wm * 32 + 16 + ln) * 40 + grp * 8];
            bf16x8 bf0 = *(const bf16x8*)&hs[(wn * 32 + ln + kt) * 40 + grp * 8];
            bf16x8 bf1 = *(const bf16x8*)&hs[(wn * 32 + 16 + ln + kt) * 40 + grp * 8];
            acc[0][0] = __builtin_amdgcn_mfma_f32_16x16x32_bf16(af0, bf0, acc[0][0], 0, 0, 0);
            acc[0][1] = __builtin_amdgcn_mfma_f32_16x16x32_bf16(af0, bf1, acc[0][1], 0, 0, 0);
            acc[1][0] = __builtin_amdgcn_mfma_f32_16x16x32_bf16(af1, bf0, acc[1][0], 0, 0, 0);
            acc[1][1] = __builtin_amdgcn_mfma_f32_16x16x32_bf16(af1, bf1, acc[1][1], 0, 0, 0);
        }
    }
    // epilogue: C/D layout col=lane&15 (n=l), row=grp*4+reg (m=o2); add bias, store fp32
    #pragma unroll
    for (int ms = 0; ms < 2; ms++) {
        int o2 = m0 + wm * 32 + ms * 16 + grp * 4;
        float4 pv = *(const float4*)&pb[o2];
        #pragma unroll
        for (int ns = 0; ns < 2; ns++) {
            int l = wn * 32 + ns * 16 + ln;
            if (l < 56) {
                float4 v;
                v.x = acc[ms][ns][0] + pv.x;
                v.y = acc[ms][ns][1] + pv.y;
                v.z = acc[ms][ns][2] + pv.z;
                v.w = acc[ms][ns][3] + pv.w;
                *(float4*)&up[(size_t)b * 43008 + (size_t)l * 768 + o2] = v;
            }
        }
    }
}

// ============ K4s: BN2 stats over up (b, l, 768) ============
__global__ void k4s(const float* __restrict__ up, float* __restrict__ sum2, float* __restrict__ ss2) {
    __shared__ float rs[256], rq[256];
    int t = threadIdx.x;
    float s = 0.f, q = 0.f;
    for (int i = 0; i < 32; i++) {
        size_t row = (size_t)(blockIdx.x * 32 + i) * 768;
        for (int c0 = 0; c0 < 768; c0 += 256) {
            float v = up[row + c0 + t];
            s += v; q += v * v;
        }
    }
    rs[t] = s; rq[t] = q;
    __syncthreads();
    if (t < 32) {
        float S = 0.f, Q = 0.f;
        for (int g2 = 0; g2 < 8; g2++) { S += rs[t + 32 * g2]; Q += rq[t + 32 * g2]; }
        atomicAdd(&sum2[t], S);
        atomicAdd(&ss2[t], Q);
    }
}

__global__ void k4b(const float* __restrict__ sum2, const float* __restrict__ ss2,
                    const float* __restrict__ g, const float* __restrict__ be,
                    float* __restrict__ a2, float* __restrict__ b2s) {
    int j = threadIdx.x;
    if (j >= 32) return;
    float m = sum2[j] * (1.f / 86016.f);
    float v = ss2[j] * (1.f / 86016.f) - m * m;
    float a = g[j] / sqrtf(v + 1e-5f);
    a2[j] = a;
    b2s[j] = be[j] - m * a;
}

// ============ K5: BN2 apply + squash over 32 -> usq (b, r, i) ============
__global__ void k5(const float* __restrict__ up, const float* __restrict__ a2,
                   const float* __restrict__ b2s, float* __restrict__ usq) {
    int t = threadIdx.x;
    int row = blockIdx.x * 8 + (t >> 5);
    int j = t & 31;
    int b = row / 1344, r = row - b * 1344;
    int p = r / 56, l = r - p * 56;
    float v = up[(size_t)b * 43008 + (size_t)l * 768 + p * 32 + j];
    float xv = a2[j] * v + b2s[j];
    float sq = xv * xv;
    #pragma unroll
    for (int m = 16; m >= 1; m >>= 1) sq += __shfl_xor(sq, m, 32);
    float scale = (sq / (1.f + sq)) / (sqrtf(sq) + 1e-8f);
    usq[(size_t)row * 32 + j] = xv * scale;
}

// ============ K6: batched GEMM per r, bf16 output ============
__global__ __launch_bounds__(256) void k6_uhat(const float* __restrict__ usq,
                                               const float* __restrict__ W,
                                               unsigned short* __restrict__ uhb) {
    __shared__ float us[64 * 36];
    __shared__ float wl[128 * 36];
    int t = threadIdx.x;
    int cdt = blockIdx.x, r = blockIdx.y;

    #pragma unroll
    for (int q = 0; q < 2; q++) {
        int idx4 = q * 256 + t;
        int b = idx4 >> 3, i4 = idx4 & 7;
        float4 v = *(const float4*)&usq[(size_t)(b * 1344 + r) * 32 + i4 * 4];
        *(float4*)&us[b * 36 + i4 * 4] = v;
    }
    #pragma unroll
    for (int q = 0; q < 4; q++) {
        int idx4 = q * 256 + t;
        int c_l = idx4 >> 7;
        int rest4 = idx4 & 127;
        float4 v = *(const float4*)&W[(size_t)(cdt * 8 + c_l) * 688128ull +
                                      (size_t)r * 512 + rest4 * 4];
        int cd_l = c_l * 16 + (rest4 >> 3);
        int i4 = rest4 & 7;
        *(float4*)&wl[cd_l * 36 + i4 * 4] = v;
    }
    __syncthreads();

    int tb = t & 7, tcd = t >> 3;
    float acc[8][4];
    #pragma unroll
    for (int i = 0; i < 8; i++)
        #pragma unroll
        for (int j = 0; j < 4; j++) acc[i][j] = 0.f;

    #pragma unroll
    for (int k4 = 0; k4 < 8; k4++) {
        float4 wv[4], ub[8];
        #pragma unroll
        for (int j = 0; j < 4; j++)
            wv[j] = *(const float4*)&wl[(tcd * 4 + j) * 36 + k4 * 4];
        #pragma unroll
        for (int bj = 0; bj < 8; bj++)
            ub[bj] = *(const float4*)&us[(bj * 8 + tb) * 36 + k4 * 4];
        #pragma unroll
        for (int bj = 0; bj < 8; bj++)
            #pragma unroll
            for (int j = 0; j < 4; j++)
                acc[bj][j] += dot4f(ub[bj], wv[j]);
    }

    #pragma unroll
    for (int bj = 0; bj < 8; bj++) {
        int b = bj * 8 + tb;
        unsigned int lo = (unsigned int)f2bf(acc[bj][0]) | ((unsigned int)f2bf(acc[bj][1]) << 16);
        unsigned int hi = (unsigned int)f2bf(acc[bj][2]) | ((unsigned int)f2bf(acc[bj][3]) << 16);
        uint2 o = {lo, hi};
        *(uint2*)&uhb[(size_t)(b * 1344 + r) * 640 + cdt * 128 + tcd * 4] = o;
    }
}

// ============ K_route: bf16 uhat, 8 r per wave, grid (42, 64) ============
template<int UNIFORM>
__global__ void k_route(const unsigned short* __restrict__ uhb, const float* __restrict__ vsum,
                        float* __restrict__ sout) {
    __shared__ float sl[2560];
    int t = threadIdx.x, wid = t >> 6, lane = t & 63;
    int b = blockIdx.y, rt = blockIdx.x;
    bool act = lane < 40;
    int c = act ? lane : 0;
    float4 vs0 = {0,0,0,0}, vs1 = vs0, vs2 = vs0, vs3 = vs0;
    if (UNIFORM == 0 && act) {
        const float4* vp = (const float4*)&vsum[b * 640 + c * 16];
        vs0 = vp[0]; vs1 = vp[1]; vs2 = vp[2]; vs3 = vp[3];
    }
    float4 ac0 = {0,0,0,0}, ac1 = ac0, ac2 = ac0, ac3 = ac0;
    for (int i = 0; i < 8; i++) {
        int r = rt * 32 + wid * 8 + i;
        const uint4* u4 = (const uint4*)&uhb[((size_t)(b * 1344 + r) * 40 + c) * 16];
        float4 a0 = {0,0,0,0}, a1 = a0, a2 = a0, a3 = a0;
        if (act) {
            uint4 q0 = u4[0], q1 = u4[1];
            a0.x = bfl(q0.x); a0.y = bfh(q0.x); a0.z = bfl(q0.y); a0.w = bfh(q0.y);
            a1.x = bfl(q0.z); a1.y = bfh(q0.z); a1.z = bfl(q0.w); a1.w = bfh(q0.w);
            a2.x = bfl(q1.x); a2.y = bfh(q1.x); a2.z = bfl(q1.y); a2.w = bfh(q1.y);
            a3.x = bfl(q1.z); a3.y = bfh(q1.z); a3.z = bfl(q1.w); a3.w = bfh(q1.w);
        }
        float w;
        if (UNIFORM) {
            w = 0.025f;
        } else {
            float dt = act ? (dot4f(a0, vs0) + dot4f(a1, vs1) + dot4f(a2, vs2) + dot4f(a3, vs3))
                           : -1e30f;
            float mx = dt;
            #pragma unroll
            for (int m2 = 32; m2 >= 1; m2 >>= 1) mx = fmaxf(mx, __shfl_xor(mx, m2));
            float e = act ? __expf(dt - mx) : 0.f;
            float se = e;
            #pragma unroll
            for (int m2 = 32; m2 >= 1; m2 >>= 1) se += __shfl_xor(se, m2);
            w = e / se;
        }
        ac0.x += w * a0.x; ac0.y += w * a0.y; ac0.z += w * a0.z; ac0.w += w * a0.w;
        ac1.x += w * a1.x; ac1.y += w * a1.y; ac1.z += w * a1.z; ac1.w += w * a1.w;
        ac2.x += w * a2.x; ac2.y += w * a2.y; ac2.z += w * a2.z; ac2.w += w * a2.w;
        ac3.x += w * a3.x; ac3.y += w * a3.y; ac3.z += w * a3.z; ac3.w += w * a3.w;
    }
    if (act) {
        float4* sp = (float4*)&sl[wid * 640 + c * 16];
        sp[0] = ac0; sp[1] = ac1; sp[2] = ac2; sp[3] = ac3;
    }
    __syncthreads();
    for (int jj = t; jj < 640; jj += 256)
        atomicAdd(&sout[b * 640 + jj], sl[jj] + sl[640 + jj] + sl[1280 + jj] + sl[1920 + jj]);
}

// ============ K8: squash s -> v ============
__global__ void k8(const float* __restrict__ sin, float* __restrict__ vout,
                   float* __restrict__ vsum, int addsum) {
    int t = threadIdx.x;
    int row = blockIdx.x * 16 + (t >> 4);
    int d = t & 15;
    float v = sin[row * 16 + d];
    float sq = v * v;
    #pragma unroll
    for (int m = 8; m >= 1; m >>= 1) sq += __shfl_xor(sq, m, 16);
    float scale = (sq / (1.f + sq)) / (sqrtf(sq) + 1e-8f);
    float o = v * scale;
    vout[row * 16 + d] = o;
    if (addsum) vsum[row * 16 + d] += o;
}

// ============ K10: head (512 thr) ============
__global__ void k10_head(const float* __restrict__ v,
                         const float* __restrict__ cw1, const float* __restrict__ cb1,
                         const float* __restrict__ cw2, const float* __restrict__ cb2,
                         const float* __restrict__ dw1, const float* __restrict__ db1,
                         const float* __restrict__ dw2, const float* __restrict__ db2,
                         float* __restrict__ out) {
    __shared__ float flat[640], hidp[512], hid[256], hd[256], lgs[40];
    __shared__ float smx, ssum;
    __shared__ int chat;
    int t = threadIdx.x, b = blockIdx.x;
    for (int j = t; j < 640; j += 512) flat[j] = v[b * 640 + j];
    __syncthreads();
    int h = t & 255, half = t >> 8;
    {
        float a = 0.f;
        int j0 = half * 320;
        for (int j = j0; j < j0 + 320; j++) a += flat[j] * cw1[h * 640 + j];
        hidp[t] = a;
    }
    __syncthreads();
    if (t < 256) hid[t] = fmaxf(hidp[t] + hidp[t + 256] + cb1[t], 0.f);
    __syncthreads();
    if (t < 320) {
        int c = t >> 3, s = t & 7;
        float p = 0.f;
        int h0 = s * 32;
        for (int h2 = h0; h2 < h0 + 32; h2++) p += hid[h2] * cw2[c * 256 + h2];
        p += __shfl_xor(p, 1); p += __shfl_xor(p, 2); p += __shfl_xor(p, 4);
        if (s == 0) lgs[c] = p + cb2[c];
    }
    __syncthreads();
    if (t == 0) {
        float mx = lgs[0]; int am = 0;
        for (int c2 = 1; c2 < 40; c2++) if (lgs[c2] > mx) { mx = lgs[c2]; am = c2; }
        float se = 0.f;
        for (int c2 = 0; c2 < 40; c2++) se += __expf(lgs[c2] - mx);
        smx = mx; ssum = se; chat = am;
    }
    __syncthreads();
    if (t < 40) out[98304 + b * 40 + t] = __expf(lgs[t] - smx) / ssum;
    int cb = chat * 16;
    if (t < 256) {
        float ad = db1[t];
        for (int j = 0; j < 16; j++) ad += flat[cb + j] * dw1[t * 640 + cb + j];
        hd[t] = fmaxf(ad, 0.f);
    }
    __syncthreads();
    for (int o = t; o < 1536; o += 512) {
        float z = db2[o];
        for (int h2 = 0; h2 < 256; h2++) z += hd[h2] * dw2[o * 256 + h2];
        out[b * 1536 + o] = 1.f / (1.f + __expf(-z));
    }
}

extern "C" void kernel_launch(void* const* d_in, const int* in_sizes, int n_in,
                              void* d_out, int out_size, void* d_ws, size_t ws_size,
                              hipStream_t stream) {
    const float* x   = (const float*)d_in[0];
    const float* c1w = (const float*)d_in[1];
    const float* c1b = (const float*)d_in[2];
    const float* g1  = (const float*)d_in[3];
    const float* be1 = (const float*)d_in[4];
    const float* pw  = (const float*)d_in[5];
    const float* pb  = (const float*)d_in[6];
    const float* g2  = (const float*)d_in[7];
    const float* be2 = (const float*)d_in[8];
    const float* Wc  = (const float*)d_in[9];
    const float* cw1 = (const float*)d_in[10];
    const float* cb1 = (const float*)d_in[11];
    const float* cw2 = (const float*)d_in[12];
    const float* cb2 = (const float*)d_in[13];
    const float* dw1 = (const float*)d_in[14];
    const float* db1 = (const float*)d_in[15];
    const float* dw2 = (const float*)d_in[16];
    const float* db2 = (const float*)d_in[17];

    if (ws_size < WS_FLOATS_NEEDED * 4ull) return;

    float* ws  = (float*)d_ws;
    float* out = (float*)d_out;
    float* usq  = ws + O_USQ;
    unsigned short* uhb = (unsigned short*)(ws + O_UHAT);
    float* hpre = ws + O_H;
    unsigned short* hbb = (unsigned short*)(ws + O_HB);
    unsigned short* wtb = (unsigned short*)(ws + O_WT);
    float* up   = ws + O_UP;
    float* sum1 = ws + O_STATS;
    float* ss1  = sum1 + 256;
    float* sum2 = ss1 + 256;
    float* ss2  = sum2 + 32;
    float* a1  = ws + O_A1;
    float* b1s = ws + O_B1S;
    float* a2  = ws + O_A2;
    float* b2s = ws + O_B2S;
    float* s0   = ws + O_S;
    float* s1   = s0 + 40960;
    float* s2   = s1 + 40960;
    float* vsum = s2 + 40960;
    float* vbuf = ws + O_V;

    hipMemsetAsync(sum1, 0, 576 * sizeof(float), stream);
    hipMemsetAsync(s0, 0, 163840 * sizeof(float), stream);

    k0w<<<768, 256, 0, stream>>>(pw, wtb);
    k1_conv1<<<dim3(4, 64, 4), 256, 0, stream>>>(x, c1w, c1b, hpre);
    k2a<<<60, 256, 0, stream>>>(hpre, sum1, ss1);
    k2b<<<1, 256, 0, stream>>>(sum1, ss1, g1, be1, a1, b1s);
    k2c<<<960, 256, 0, stream>>>(hpre, a1, b1s, hbb);
    k3_mfma<<<dim3(12, 64), 256, 0, stream>>>(hbb, wtb, pb, up);
    k4s<<<112, 256, 0, stream>>>(up, sum2, ss2);
    k4b<<<1, 64, 0, stream>>>(sum2, ss2, g2, be2, a2, b2s);
    k5<<<10752, 256, 0, stream>>>(up, a2, b2s, usq);
    k6_uhat<<<dim3(5, 1344), 256, 0, stream>>>(usq, Wc, uhb);
    k_route<1><<<dim3(42, 64), 256, 0, stream>>>(uhb, nullptr, s0);
    k8<<<160, 256, 0, stream>>>(s0, vbuf, vsum, 1);
    k_route<0><<<dim3(42, 64), 256, 0, stream>>>(uhb, vsum, s1);
    k8<<<160, 256, 0, stream>>>(s1, vbuf, vsum, 1);
    k_route<0><<<dim3(42, 64), 256, 0, stream>>>(uhb, vsum, s2);
    k8<<<160, 256, 0, stream>>>(s2, vbuf, vsum, 0);
    k10_head<<<64, 512, 0, stream>>>(vbuf, cw1, cb1, cw2, cb2, dw1, db1, dw2, db2, out);
}

// Round 2
// 381.469 us; speedup vs baseline: 1.3836x; 1.1182x over previous
//
#include <hip/hip_runtime.h>
#include <math.h>

// ---------------- problem constants ----------------
#define BB_ 64
#define P_  24
#define C_  40
#define WIN_ 64
#define L1_ 60
#define L2_ 56
#define R_  1344

// ---------------- ws layout (float offsets) ----------------
// usq [0, 2752512)
// uhat (bf16, 55050240 ushorts = 27525120 floats) at [2752512, 30277632)
// hb/wt/up overlay inside uhat region (dead before k6 writes uhat)
#define O_USQ   0ull
#define O_UHAT  2752512ull
#define O_H     30277632ull         // hpre: 64*60*256 = 983040 floats (outside uhat region)
#define O_HB    3735552ull          // bf16 h: 983040 ushorts = 491520 floats
#define O_WT    4227072ull          // bf16 wt: 983040 ushorts = 491520 floats
#define O_UP    25755648ull         // 2752512 floats, alias in uhat region
#define O_HID   31260672ull         // head hidden: 64*256 floats (dead hole after hpre)
#define O_HD    31277056ull         // decoder hidden: 64*256 floats
#define O_STATS 57802752ull
#define O_A1    57803328ull
#define O_B1S   57803584ull
#define O_A2    57803840ull
#define O_B2S   57803872ull
#define O_S     57803904ull         // s0,s1,s2,vsum each 40960
#define O_V     57967744ull
#define WS_FLOATS_NEEDED 58008704ull

typedef short bf16x8 __attribute__((ext_vector_type(8)));
typedef float f32x4 __attribute__((ext_vector_type(4)));

__device__ __forceinline__ float dot4f(float4 a, float4 b) {
    return a.x*b.x + a.y*b.y + a.z*b.z + a.w*b.w;
}

__device__ __forceinline__ unsigned short f2bf(float x) {
    unsigned int u = __float_as_uint(x);
    u += 0x7fffu + ((u >> 16) & 1u);       // RTNE
    return (unsigned short)(u >> 16);
}
__device__ __forceinline__ float bfl(unsigned int u) {   // low ushort -> float
    return __uint_as_float(u << 16);
}
__device__ __forceinline__ float bfh(unsigned int u) {   // high ushort -> float
    return __uint_as_float(u & 0xffff0000u);
}

// ============ K0w: transpose prim_w (768,256,5) -> bf16 wt[kt][o2][ic] ============
__global__ void k0w(const float* __restrict__ w2, unsigned short* __restrict__ wt) {
    int o2 = blockIdx.x, t = threadIdx.x;   // t = ic (0..255)
    const float* src = &w2[(size_t)o2 * 1280 + t * 5];
    #pragma unroll
    for (int kt = 0; kt < 5; kt++)
        wt[((size_t)kt * 768 + o2) * 256 + t] = f2bf(src[kt]);
}

// ============ K1: conv1 (24->256, k=5) + bias, h layout (b, l, o) ============
__global__ void k1_conv1(const float* __restrict__ x, const float* __restrict__ w1,
                         const float* __restrict__ c1b, float* __restrict__ h) {
    __shared__ float xs[24 * 20];
    __shared__ float wl[64 * 121];
    int t = threadIdx.x;
    int lq = blockIdx.x, b = blockIdx.y, ocg = blockIdx.z;
    for (int idx = t; idx < 456; idx += 256) {
        int p = idx / 19, tau = idx - p * 19;
        xs[p * 20 + tau] = x[b * 1536 + (lq * 15 + tau) * 24 + p];
    }
    for (int idx = t; idx < 7680; idx += 256) {
        int o_ = idx / 120, cix = idx - o_ * 120;
        wl[o_ * 121 + cix] = w1[(ocg * 64 + o_) * 120 + cix];
    }
    __syncthreads();
    int g = t >> 6;
    int ol = t & 63;
    int LV = (g < 3) ? 4 : 3;
    int o = ocg * 64 + ol;
    float acc[4] = {0.f, 0.f, 0.f, 0.f};
    for (int p = 0; p < 24; p++) {
        float4 xa = *(const float4*)&xs[p * 20 + g * 4];
        float4 xb = *(const float4*)&xs[p * 20 + g * 4 + 4];
        float xr[8] = {xa.x, xa.y, xa.z, xa.w, xb.x, xb.y, xb.z, xb.w};
        #pragma unroll
        for (int k = 0; k < 5; k++) {
            float w = wl[ol * 121 + p * 5 + k];
            #pragma unroll
            for (int li = 0; li < 4; li++) acc[li] += xr[li + k] * w;
        }
    }
    for (int li = 0; li < LV; li++) {
        int l = lq * 15 + g * 4 + li;
        h[(size_t)(b * 60 + l) * 256 + o] = acc[li] + c1b[o];
    }
}

// ============ K2a: BN1 stats ============
__global__ void k2a(const float* __restrict__ h, float* __restrict__ sum1, float* __restrict__ ss1) {
    int t = threadIdx.x;
    float s = 0.f, q = 0.f;
    for (int i = 0; i < 64; i++) {
        float v = h[(size_t)(blockIdx.x * 64 + i) * 256 + t];
        s += v; q += v * v;
    }
    atomicAdd(&sum1[t], s);
    atomicAdd(&ss1[t], q);
}

__global__ void k2b(const float* __restrict__ sum1, const float* __restrict__ ss1,
                    const float* __restrict__ g, const float* __restrict__ be,
                    float* __restrict__ a1, float* __restrict__ b1s) {
    int o = threadIdx.x;
    float m = sum1[o] * (1.f / 3840.f);
    float v = ss1[o] * (1.f / 3840.f) - m * m;
    float a = g[o] / sqrtf(v + 1e-5f);
    a1[o] = a;
    b1s[o] = be[o] - m * a;
}

// ============ K2c: BN1+ReLU apply + bf16 convert -> hb[b][l][ic] ============
__global__ void k2c(const float* __restrict__ h, const float* __restrict__ a1,
                    const float* __restrict__ b1s, unsigned short* __restrict__ hb) {
    int gid = blockIdx.x * 256 + threadIdx.x;   // 0..245759
    int base = gid * 4;
    int ic = base & 255;
    float4 v = *(const float4*)&h[base];
    float4 a = *(const float4*)&a1[ic];
    float4 bb = *(const float4*)&b1s[ic];
    unsigned int w0 = (unsigned int)f2bf(fmaxf(v.x * a.x + bb.x, 0.f))
                    | ((unsigned int)f2bf(fmaxf(v.y * a.y + bb.y, 0.f)) << 16);
    unsigned int w1 = (unsigned int)f2bf(fmaxf(v.z * a.z + bb.z, 0.f))
                    | ((unsigned int)f2bf(fmaxf(v.w * a.w + bb.w, 0.f)) << 16);
    uint2 o = {w0, w1};
    *(uint2*)&hb[base] = o;
}

// ============ K3: primary conv as bf16 MFMA GEMM ============
__global__ __launch_bounds__(256) void k3_mfma(
        const unsigned short* __restrict__ hb, const unsigned short* __restrict__ wt,
        const float* __restrict__ pb, float* __restrict__ up) {
    __shared__ unsigned short hs[68 * 40];        // rows l=0..67 (clamped to 59), 32 ic + pad
    __shared__ unsigned short wsd[5 * 64 * 40];   // [kt][o2_local][ic + pad]
    int t = threadIdx.x;
    int m0 = blockIdx.x * 64;
    int b = blockIdx.y;
    int wid = t >> 6, lane = t & 63;
    int wm = wid >> 1, wn = wid & 1;
    int ln = lane & 15, grp = lane >> 4;

    f32x4 acc[2][2];
    #pragma unroll
    for (int i = 0; i < 2; i++)
        #pragma unroll
        for (int j = 0; j < 2; j++) acc[i][j] = (f32x4){0.f, 0.f, 0.f, 0.f};

    for (int ic0 = 0; ic0 < 256; ic0 += 32) {
        __syncthreads();
        // stage h: 68 rows x 32 ic (bf16), 272 uint4
        for (int idx = t; idx < 272; idx += 256) {
            int row = idx >> 2, q = idx & 3;
            int hrow = row < 60 ? row : 59;      // rows >=60 feed only discarded cols
            uint4 v = *(const uint4*)&hb[((size_t)b * 60 + hrow) * 256 + ic0 + q * 8];
            *(uint4*)&hs[row * 40 + q * 8] = v;
        }
        // stage W: 5 kt x 64 o2 x 32 ic (bf16), 1280 uint4
        #pragma unroll
        for (int it = 0; it < 5; it++) {
            int idx = it * 256 + t;
            int row = idx >> 2, q = idx & 3;     // row = kt*64 + o2l
            int kt = row >> 6, o2l = row & 63;
            uint4 v = *(const uint4*)&wt[((size_t)kt * 768 + m0 + o2l) * 256 + ic0 + q * 8];
            *(uint4*)&wsd[row * 40 + q * 8] = v;
        }
        __syncthreads();
        #pragma unroll
        for (int kt = 0; kt < 5; kt++) {
            bf16x8 af0 = *(const bf16x8*)&wsd[(kt * 64 + wm * 32 + ln) * 40 + grp * 8];
            bf16x8 af1 = *(const bf16x8*)&wsd[(kt * 64 + wm * 32 + 16 + ln) * 40 + grp * 8];
            bf16x8 bf0 = *(const bf16x8*)&hs[(wn * 32 + ln + kt) * 40 + grp * 8];
            bf16x8 bf1 = *(const bf16x8*)&hs[(wn * 32 + 16 + ln + kt) * 40 + grp * 8];
            acc[0][0] = __builtin_amdgcn_mfma_f32_16x16x32_bf16(af0, bf0, acc[0][0], 0, 0, 0);
            acc[0][1] = __builtin_amdgcn_mfma_f32_16x16x32_bf16(af0, bf1, acc[0][1], 0, 0, 0);
            acc[1][0] = __builtin_amdgcn_mfma_f32_16x16x32_bf16(af1, bf0, acc[1][0], 0, 0, 0);
            acc[1][1] = __builtin_amdgcn_mfma_f32_16x16x32_bf16(af1, bf1, acc[1][1], 0, 0, 0);
        }
    }
    // epilogue: C/D layout col=lane&15 (n=l), row=grp*4+reg (m=o2); add bias, store fp32
    #pragma unroll
    for (int ms = 0; ms < 2; ms++) {
        int o2 = m0 + wm * 32 + ms * 16 + grp * 4;
        float4 pv = *(const float4*)&pb[o2];
        #pragma unroll
        for (int ns = 0; ns < 2; ns++) {
            int l = wn * 32 + ns * 16 + ln;
            if (l < 56) {
                float4 v;
                v.x = acc[ms][ns][0] + pv.x;
                v.y = acc[ms][ns][1] + pv.y;
                v.z = acc[ms][ns][2] + pv.z;
                v.w = acc[ms][ns][3] + pv.w;
                *(float4*)&up[(size_t)b * 43008 + (size_t)l * 768 + o2] = v;
            }
        }
    }
}

// ============ K4s: BN2 stats over up (b, l, 768) ============
__global__ void k4s(const float* __restrict__ up, float* __restrict__ sum2, float* __restrict__ ss2) {
    __shared__ float rs[256], rq[256];
    int t = threadIdx.x;
    float s = 0.f, q = 0.f;
    for (int i = 0; i < 32; i++) {
        size_t row = (size_t)(blockIdx.x * 32 + i) * 768;
        for (int c0 = 0; c0 < 768; c0 += 256) {
            float v = up[row + c0 + t];
            s += v; q += v * v;
        }
    }
    rs[t] = s; rq[t] = q;
    __syncthreads();
    if (t < 32) {
        float S = 0.f, Q = 0.f;
        for (int g2 = 0; g2 < 8; g2++) { S += rs[t + 32 * g2]; Q += rq[t + 32 * g2]; }
        atomicAdd(&sum2[t], S);
        atomicAdd(&ss2[t], Q);
    }
}

__global__ void k4b(const float* __restrict__ sum2, const float* __restrict__ ss2,
                    const float* __restrict__ g, const float* __restrict__ be,
                    float* __restrict__ a2, float* __restrict__ b2s) {
    int j = threadIdx.x;
    if (j >= 32) return;
    float m = sum2[j] * (1.f / 86016.f);
    float v = ss2[j] * (1.f / 86016.f) - m * m;
    float a = g[j] / sqrtf(v + 1e-5f);
    a2[j] = a;
    b2s[j] = be[j] - m * a;
}

// ============ K5: BN2 apply + squash over 32 -> usq (b, r, i) ============
__global__ void k5(const float* __restrict__ up, const float* __restrict__ a2,
                   const float* __restrict__ b2s, float* __restrict__ usq) {
    int t = threadIdx.x;
    int row = blockIdx.x * 8 + (t >> 5);
    int j = t & 31;
    int b = row / 1344, r = row - b * 1344;
    int p = r / 56, l = r - p * 56;
    float v = up[(size_t)b * 43008 + (size_t)l * 768 + p * 32 + j];
    float xv = a2[j] * v + b2s[j];
    float sq = xv * xv;
    #pragma unroll
    for (int m = 16; m >= 1; m >>= 1) sq += __shfl_xor(sq, m, 32);
    float scale = (sq / (1.f + sq)) / (sqrtf(sq) + 1e-8f);
    usq[(size_t)row * 32 + j] = xv * scale;
}

// ============ K6: batched GEMM per r, bf16 output ============
__global__ __launch_bounds__(256) void k6_uhat(const float* __restrict__ usq,
                                               const float* __restrict__ W,
                                               unsigned short* __restrict__ uhb) {
    __shared__ float us[64 * 36];
    __shared__ float wl[128 * 36];
    int t = threadIdx.x;
    int cdt = blockIdx.x, r = blockIdx.y;

    #pragma unroll
    for (int q = 0; q < 2; q++) {
        int idx4 = q * 256 + t;
        int b = idx4 >> 3, i4 = idx4 & 7;
        float4 v = *(const float4*)&usq[(size_t)(b * 1344 + r) * 32 + i4 * 4];
        *(float4*)&us[b * 36 + i4 * 4] = v;
    }
    #pragma unroll
    for (int q = 0; q < 4; q++) {
        int idx4 = q * 256 + t;
        int c_l = idx4 >> 7;
        int rest4 = idx4 & 127;
        float4 v = *(const float4*)&W[(size_t)(cdt * 8 + c_l) * 688128ull +
                                      (size_t)r * 512 + rest4 * 4];
        int cd_l = c_l * 16 + (rest4 >> 3);
        int i4 = rest4 & 7;
        *(float4*)&wl[cd_l * 36 + i4 * 4] = v;
    }
    __syncthreads();

    int tb = t & 7, tcd = t >> 3;
    float acc[8][4];
    #pragma unroll
    for (int i = 0; i < 8; i++)
        #pragma unroll
        for (int j = 0; j < 4; j++) acc[i][j] = 0.f;

    #pragma unroll
    for (int k4 = 0; k4 < 8; k4++) {
        float4 wv[4], ub[8];
        #pragma unroll
        for (int j = 0; j < 4; j++)
            wv[j] = *(const float4*)&wl[(tcd * 4 + j) * 36 + k4 * 4];
        #pragma unroll
        for (int bj = 0; bj < 8; bj++)
            ub[bj] = *(const float4*)&us[(bj * 8 + tb) * 36 + k4 * 4];
        #pragma unroll
        for (int bj = 0; bj < 8; bj++)
            #pragma unroll
            for (int j = 0; j < 4; j++)
                acc[bj][j] += dot4f(ub[bj], wv[j]);
    }

    #pragma unroll
    for (int bj = 0; bj < 8; bj++) {
        int b = bj * 8 + tb;
        unsigned int lo = (unsigned int)f2bf(acc[bj][0]) | ((unsigned int)f2bf(acc[bj][1]) << 16);
        unsigned int hi = (unsigned int)f2bf(acc[bj][2]) | ((unsigned int)f2bf(acc[bj][3]) << 16);
        uint2 o = {lo, hi};
        *(uint2*)&uhb[(size_t)(b * 1344 + r) * 640 + cdt * 128 + tcd * 4] = o;
    }
}

// ============ K_route: bf16 uhat, 8 r per wave, grid (42, 64) ============
template<int UNIFORM>
__global__ void k_route(const unsigned short* __restrict__ uhb, const float* __restrict__ vsum,
                        float* __restrict__ sout) {
    __shared__ float sl[2560];
    int t = threadIdx.x, wid = t >> 6, lane = t & 63;
    int b = blockIdx.y, rt = blockIdx.x;
    bool act = lane < 40;
    int c = act ? lane : 0;
    float4 vs0 = {0,0,0,0}, vs1 = vs0, vs2 = vs0, vs3 = vs0;
    if (UNIFORM == 0 && act) {
        const float4* vp = (const float4*)&vsum[b * 640 + c * 16];
        vs0 = vp[0]; vs1 = vp[1]; vs2 = vp[2]; vs3 = vp[3];
    }
    float4 ac0 = {0,0,0,0}, ac1 = ac0, ac2 = ac0, ac3 = ac0;
    for (int i = 0; i < 8; i++) {
        int r = rt * 32 + wid * 8 + i;
        const uint4* u4 = (const uint4*)&uhb[((size_t)(b * 1344 + r) * 40 + c) * 16];
        float4 a0 = {0,0,0,0}, a1 = a0, a2 = a0, a3 = a0;
        if (act) {
            uint4 q0 = u4[0], q1 = u4[1];
            a0.x = bfl(q0.x); a0.y = bfh(q0.x); a0.z = bfl(q0.y); a0.w = bfh(q0.y);
            a1.x = bfl(q0.z); a1.y = bfh(q0.z); a1.z = bfl(q0.w); a1.w = bfh(q0.w);
            a2.x = bfl(q1.x); a2.y = bfh(q1.x); a2.z = bfl(q1.y); a2.w = bfh(q1.y);
            a3.x = bfl(q1.z); a3.y = bfh(q1.z); a3.z = bfl(q1.w); a3.w = bfh(q1.w);
        }
        float w;
        if (UNIFORM) {
            w = 0.025f;
        } else {
            float dt = act ? (dot4f(a0, vs0) + dot4f(a1, vs1) + dot4f(a2, vs2) + dot4f(a3, vs3))
                           : -1e30f;
            float mx = dt;
            #pragma unroll
            for (int m2 = 32; m2 >= 1; m2 >>= 1) mx = fmaxf(mx, __shfl_xor(mx, m2));
            float e = act ? __expf(dt - mx) : 0.f;
            float se = e;
            #pragma unroll
            for (int m2 = 32; m2 >= 1; m2 >>= 1) se += __shfl_xor(se, m2);
            w = e / se;
        }
        ac0.x += w * a0.x; ac0.y += w * a0.y; ac0.z += w * a0.z; ac0.w += w * a0.w;
        ac1.x += w * a1.x; ac1.y += w * a1.y; ac1.z += w * a1.z; ac1.w += w * a1.w;
        ac2.x += w * a2.x; ac2.y += w * a2.y; ac2.z += w * a2.z; ac2.w += w * a2.w;
        ac3.x += w * a3.x; ac3.y += w * a3.y; ac3.z += w * a3.z; ac3.w += w * a3.w;
    }
    if (act) {
        float4* sp = (float4*)&sl[wid * 640 + c * 16];
        sp[0] = ac0; sp[1] = ac1; sp[2] = ac2; sp[3] = ac3;
    }
    __syncthreads();
    for (int jj = t; jj < 640; jj += 256)
        atomicAdd(&sout[b * 640 + jj], sl[jj] + sl[640 + jj] + sl[1280 + jj] + sl[1920 + jj]);
}

// ============ K8: squash s -> v ============
__global__ void k8(const float* __restrict__ sin, float* __restrict__ vout,
                   float* __restrict__ vsum, int addsum) {
    int t = threadIdx.x;
    int row = blockIdx.x * 16 + (t >> 4);
    int d = t & 15;
    float v = sin[row * 16 + d];
    float sq = v * v;
    #pragma unroll
    for (int m = 8; m >= 1; m >>= 1) sq += __shfl_xor(sq, m, 16);
    float scale = (sq / (1.f + sq)) / (sqrtf(sq) + 1e-8f);
    float o = v * scale;
    vout[row * 16 + d] = o;
    if (addsum) vsum[row * 16 + d] += o;
}

// ============ K10a: hid = ReLU(flat @ cw1^T + cb1), grid (64 b, 4 hq) ============
__global__ void k10a(const float* __restrict__ v, const float* __restrict__ cw1,
                     const float* __restrict__ cb1, float* __restrict__ hid) {
    __shared__ float flat[640];
    int t = threadIdx.x;
    int b = blockIdx.x, hq = blockIdx.y;
    for (int j = t; j < 640; j += 256) flat[j] = v[b * 640 + j];
    __syncthreads();
    int h_l = t >> 2, s = t & 3;
    int h = hq * 64 + h_l;
    const float4* wr = (const float4*)&cw1[(size_t)h * 640 + s * 160];
    float a = 0.f;
    #pragma unroll
    for (int u = 0; u < 40; u++) {
        float4 w4 = wr[u];
        float4 f4 = *(const float4*)&flat[s * 160 + u * 4];
        a += dot4f(w4, f4);
    }
    a += __shfl_xor(a, 1);
    a += __shfl_xor(a, 2);
    if (s == 0) hid[b * 256 + h] = fmaxf(a + cb1[h], 0.f);
}

// ============ K10bc: logits + softmax + argmax + pred_y + decoder hidden ============
__global__ void k10bc(const float* __restrict__ v, const float* __restrict__ hid,
                      const float* __restrict__ cw2, const float* __restrict__ cb2,
                      const float* __restrict__ dw1, const float* __restrict__ db1,
                      float* __restrict__ out, float* __restrict__ hd) {
    __shared__ float hl[256], lgs[40], msk[16];
    __shared__ float smx, ssum;
    __shared__ int chat;
    int t = threadIdx.x, b = blockIdx.x;
    if (t < 256) hl[t] = hid[b * 256 + t];
    __syncthreads();
    {   // logits: 40 c x 8 splits of K=256
        int c = t >> 3, s = t & 7;
        float p = 0.f;
        const float4* w4 = (const float4*)&cw2[c * 256 + s * 32];
        const float4* h4 = (const float4*)&hl[s * 32];
        #pragma unroll
        for (int u = 0; u < 8; u++) p += dot4f(w4[u], h4[u]);
        p += __shfl_xor(p, 1); p += __shfl_xor(p, 2); p += __shfl_xor(p, 4);
        if (s == 0) lgs[c] = p + cb2[c];
    }
    __syncthreads();
    if (t == 0) {
        float mx = lgs[0]; int am = 0;
        for (int c2 = 1; c2 < 40; c2++) if (lgs[c2] > mx) { mx = lgs[c2]; am = c2; }
        float se = 0.f;
        for (int c2 = 0; c2 < 40; c2++) se += __expf(lgs[c2] - mx);
        smx = mx; ssum = se; chat = am;
    }
    __syncthreads();
    if (t < 40) out[98304 + b * 40 + t] = __expf(lgs[t] - smx) / ssum;
    if (t < 16) msk[t] = v[b * 640 + chat * 16 + t];
    __syncthreads();
    if (t < 256) {
        int cb = chat * 16;
        float ad = db1[t];
        const float4* w4 = (const float4*)&dw1[(size_t)t * 640 + cb];
        #pragma unroll
        for (int u = 0; u < 4; u++) {
            float4 m4 = *(const float4*)&msk[u * 4];
            ad += dot4f(w4[u], m4);
        }
        hd[b * 256 + t] = fmaxf(ad, 0.f);
    }
}

// ============ K10d: out = sigmoid(hd @ dw2^T + db2), grid (64 b, 24 ot) ============
__global__ void k10d(const float* __restrict__ hd, const float* __restrict__ dw2,
                     const float* __restrict__ db2, float* __restrict__ out) {
    __shared__ float hl[256];
    int t = threadIdx.x;
    int b = blockIdx.x, ot = blockIdx.y;
    if (t < 256) hl[t] = hd[b * 256 + t];
    __syncthreads();
    int o_l = t >> 2, s = t & 3;
    int o = ot * 64 + o_l;
    const float4* w4 = (const float4*)&dw2[(size_t)o * 256 + s * 64];
    const float4* h4 = (const float4*)&hl[s * 64];
    float z = 0.f;
    #pragma unroll
    for (int u = 0; u < 16; u++) z += dot4f(w4[u], h4[u]);
    z += __shfl_xor(z, 1);
    z += __shfl_xor(z, 2);
    if (s == 0) out[b * 1536 + o] = 1.f / (1.f + __expf(-(z + db2[o])));
}

extern "C" void kernel_launch(void* const* d_in, const int* in_sizes, int n_in,
                              void* d_out, int out_size, void* d_ws, size_t ws_size,
                              hipStream_t stream) {
    const float* x   = (const float*)d_in[0];
    const float* c1w = (const float*)d_in[1];
    const float* c1b = (const float*)d_in[2];
    const float* g1  = (const float*)d_in[3];
    const float* be1 = (const float*)d_in[4];
    const float* pw  = (const float*)d_in[5];
    const float* pb  = (const float*)d_in[6];
    const float* g2  = (const float*)d_in[7];
    const float* be2 = (const float*)d_in[8];
    const float* Wc  = (const float*)d_in[9];
    const float* cw1 = (const float*)d_in[10];
    const float* cb1 = (const float*)d_in[11];
    const float* cw2 = (const float*)d_in[12];
    const float* cb2 = (const float*)d_in[13];
    const float* dw1 = (const float*)d_in[14];
    const float* db1 = (const float*)d_in[15];
    const float* dw2 = (const float*)d_in[16];
    const float* db2 = (const float*)d_in[17];

    if (ws_size < WS_FLOATS_NEEDED * 4ull) return;

    float* ws  = (float*)d_ws;
    float* out = (float*)d_out;
    float* usq  = ws + O_USQ;
    unsigned short* uhb = (unsigned short*)(ws + O_UHAT);
    float* hpre = ws + O_H;
    unsigned short* hbb = (unsigned short*)(ws + O_HB);
    unsigned short* wtb = (unsigned short*)(ws + O_WT);
    float* up   = ws + O_UP;
    float* hidb = ws + O_HID;
    float* hdb  = ws + O_HD;
    float* sum1 = ws + O_STATS;
    float* ss1  = sum1 + 256;
    float* sum2 = ss1 + 256;
    float* ss2  = sum2 + 32;
    float* a1  = ws + O_A1;
    float* b1s = ws + O_B1S;
    float* a2  = ws + O_A2;
    float* b2s = ws + O_B2S;
    float* s0   = ws + O_S;
    float* s1   = s0 + 40960;
    float* s2   = s1 + 40960;
    float* vsum = s2 + 40960;
    float* vbuf = ws + O_V;

    hipMemsetAsync(sum1, 0, 576 * sizeof(float), stream);
    hipMemsetAsync(s0, 0, 163840 * sizeof(float), stream);

    k0w<<<768, 256, 0, stream>>>(pw, wtb);
    k1_conv1<<<dim3(4, 64, 4), 256, 0, stream>>>(x, c1w, c1b, hpre);
    k2a<<<60, 256, 0, stream>>>(hpre, sum1, ss1);
    k2b<<<1, 256, 0, stream>>>(sum1, ss1, g1, be1, a1, b1s);
    k2c<<<960, 256, 0, stream>>>(hpre, a1, b1s, hbb);
    k3_mfma<<<dim3(12, 64), 256, 0, stream>>>(hbb, wtb, pb, up);
    k4s<<<112, 256, 0, stream>>>(up, sum2, ss2);
    k4b<<<1, 64, 0, stream>>>(sum2, ss2, g2, be2, a2, b2s);
    k5<<<10752, 256, 0, stream>>>(up, a2, b2s, usq);
    k6_uhat<<<dim3(5, 1344), 256, 0, stream>>>(usq, Wc, uhb);
    k_route<1><<<dim3(42, 64), 256, 0, stream>>>(uhb, nullptr, s0);
    k8<<<160, 256, 0, stream>>>(s0, vbuf, vsum, 1);
    k_route<0><<<dim3(42, 64), 256, 0, stream>>>(uhb, vsum, s1);
    k8<<<160, 256, 0, stream>>>(s1, vbuf, vsum, 1);
    k_route<0><<<dim3(42, 64), 256, 0, stream>>>(uhb, vsum, s2);
    k8<<<160, 256, 0, stream>>>(s2, vbuf, vsum, 0);
    k10a<<<dim3(64, 4), 256, 0, stream>>>(vbuf, cw1, cb1, hidb);
    k10bc<<<64, 320, 0, stream>>>(vbuf, hidb, cw2, cb2, dw1, db1, out, hdb);
    k10d<<<dim3(64, 24), 256, 0, stream>>>(hdb, dw2, db2, out);
}